// Round 1
// baseline (298.452 us; speedup 1.0000x reference)
//
#include <hip/hip_runtime.h>
#include <hip/hip_bf16.h>

// GCN stack: N=50000 nodes, E=600000 edges, D=128.
//  1. prep0: zero cnt + (W1,R1,W2,R2 -> f16 transposed; Wc=W3@Wh -> f16 T)
//  2. hist col -> cnt; fused hierarchical scan -> row_ptr/cursor (+dinv);
//     fill CSR by dest (entry: ushort src id only)
//  3. gemm_dual<1>: x -> H1'(=H1*dinv),XR1; spmm: x1; gemm_dual<0>: ->
//     H2',XR2; spmm: x2; gemm_h(Wc): G'; spmm_final: out = dinv*(A@G') + bh
//
// R1: single-block scan -> hierarchical (634->542)
// R2: fp32 VALU GEMM -> f16 MFMA; SpMM unroll x4 (542->422)
// R3: all activations f16 (422->340)
// R4: SpMM 16B/lane + dual-GEMM fusion (340->317)
// R5: head folded into Wc=W3@Wh (317->316)
// R6: SpMM 1 node/16-lane sub; csr 8B->4B (316->296)
// R7 FAILED: SpMM+GEMM fusion -> 17% occupancy (52KB LDS, 3 blk/CU) strangled
//     the latency-bound gather phase (49.7us vs ~20+7 split). Lesson: keep
//     gather kernels LDS-free / high-occupancy. (296->299)
// R8: revert fusion (R6 structure), keep prep0 merge, SpMM unroll 4->8.
// R9: norm separability: agg[c] = dinv[c]*(sum dinv[r]h[r] + dinv[c]h[c]).
//     dinv[r] folded into GEMM epilogue (H' = H*dinv), dinv[c] applied once
//     per node in SpMM. fill loses BOTH per-edge random dinv gathers; csr
//     entry 4B->2B (ushort src). 3 scan kernels fused into 1 (nb=49: each
//     block redundantly sums preceding cnt region).

#define SCAN_CHUNK 1024

typedef _Float16 half8 __attribute__((ext_vector_type(8)));
typedef _Float16 half4 __attribute__((ext_vector_type(4)));
typedef float floatx4 __attribute__((ext_vector_type(4)));

// blocks [0, nzb): zero cnt. blocks [nzb, nzb+64): wcvt. [nzb+64, nzb+80): Wc.
__global__ __launch_bounds__(256) void prep0_kernel(
        int* __restrict__ cnt, int n, int nzb,
        const float* __restrict__ W1, const float* __restrict__ R1,
        const float* __restrict__ W2, const float* __restrict__ R2,
        const float* __restrict__ W3, const float* __restrict__ Wh,
        _Float16* __restrict__ Wt) {
    int b = blockIdx.x;
    int t = threadIdx.x;
    if (b < nzb) {
        int i = b * 256 + t;
        if (i < n) cnt[i] = 0;
        return;
    }
    int b2 = b - nzb;
    if (b2 < 64) {
        __shared__ float tile[32][33];
        int mat = b2 >> 4, tl = b2 & 15;
        const float* W = (mat == 0) ? W1 : (mat == 1) ? R1 : (mat == 2) ? W2 : R2;
        _Float16* T = Wt + (size_t)mat * 16384;
        int tr = (tl >> 2) * 32, tc = (tl & 3) * 32;
        int i = t >> 3, j4 = t & 7;
        float4 v = *(const float4*)&W[(tr + i) * 128 + tc + j4 * 4];
        tile[i][j4 * 4 + 0] = v.x;
        tile[i][j4 * 4 + 1] = v.y;
        tile[i][j4 * 4 + 2] = v.z;
        tile[i][j4 * 4 + 3] = v.w;
        __syncthreads();
        half4 h;
        h.x = (_Float16)tile[j4 * 4 + 0][i];
        h.y = (_Float16)tile[j4 * 4 + 1][i];
        h.z = (_Float16)tile[j4 * 4 + 2][i];
        h.w = (_Float16)tile[j4 * 4 + 3][i];
        *(half4*)&T[(tc + i) * 128 + tr + j4 * 4] = h;
    } else {
        int bb = b2 - 64;
        _Float16* Wtc = Wt + (size_t)4 * 16384;
        int c = bb * 8 + (t >> 5);
        int k0 = (t & 31) * 4;
        float acc0 = 0.f, acc1 = 0.f, acc2 = 0.f, acc3 = 0.f;
        for (int j = 0; j < 128; ++j) {
            float wh = Wh[j * 128 + c];
            acc0 = fmaf(W3[(k0 + 0) * 128 + j], wh, acc0);
            acc1 = fmaf(W3[(k0 + 1) * 128 + j], wh, acc1);
            acc2 = fmaf(W3[(k0 + 2) * 128 + j], wh, acc2);
            acc3 = fmaf(W3[(k0 + 3) * 128 + j], wh, acc3);
        }
        half4 h;
        h.x = (_Float16)acc0; h.y = (_Float16)acc1;
        h.z = (_Float16)acc2; h.w = (_Float16)acc3;
        *(half4*)&Wtc[c * 128 + k0] = h;
    }
}

__global__ void hist_kernel(const int* __restrict__ col, int* __restrict__ cnt, int E) {
    int i = blockIdx.x * blockDim.x + threadIdx.x;
    if (i < E) atomicAdd(&cnt[col[i]], 1);
}

// Fused hierarchical scan: nb blocks; block b first redundantly sums all
// cnt values of preceding chunks (<= 48KB coalesced, trivial), then scans
// its own chunk and writes row_ptr/cursor/dinv.
__global__ __launch_bounds__(256) void scan_fused_kernel(
        const int* __restrict__ cnt, int* __restrict__ row_ptr,
        int* __restrict__ cursor, float* __restrict__ dinv, int n, int E) {
    __shared__ int s[256];
    int b = blockIdx.x, t = threadIdx.x;

    // phase A: offset = sum of cnt[0 .. b*SCAN_CHUNK)
    int tot = 0;
    int lim = b * SCAN_CHUNK;   // multiple of 1024, always <= last full region < n
    for (int i = t * 4; i < lim; i += 1024) {
        int4 q = *(const int4*)&cnt[i];
        tot += q.x + q.y + q.z + q.w;
    }
    s[t] = tot;
    __syncthreads();
    for (int off = 128; off > 0; off >>= 1) {
        if (t < off) s[t] += s[t + off];
        __syncthreads();
    }
    int boffb = s[0];
    __syncthreads();

    // phase B: local chunk scan + outputs
    int base = b * SCAN_CHUNK + t * 4;
    int v[4];
    int sum = 0;
    for (int i = 0; i < 4; ++i) {
        v[i] = (base + i < n) ? cnt[base + i] : 0;
        sum += v[i];
    }
    s[t] = sum;
    __syncthreads();
    for (int off = 1; off < 256; off <<= 1) {
        int add = (t >= off) ? s[t - off] : 0;
        __syncthreads();
        s[t] += add;
        __syncthreads();
    }
    int prefix = boffb + ((t == 0) ? 0 : s[t - 1]);
    for (int i = 0; i < 4; ++i) {
        if (base + i < n) {
            row_ptr[base + i] = prefix;
            cursor[base + i] = prefix;
            dinv[base + i] = rsqrtf((float)(v[i] + 1));
            prefix += v[i];
        }
    }
    if (b == 0 && t == 0) row_ptr[n] = E;
}

// csr entry: ushort src node id (N<65536). No per-edge norm anymore.
__global__ void fill_kernel(const int* __restrict__ row, const int* __restrict__ colv,
                            int* __restrict__ cursor,
                            unsigned short* __restrict__ csr, int E) {
    int i = blockIdx.x * blockDim.x + threadIdx.x;
    if (i < E) {
        int c = colv[i];
        int p = atomicAdd(&cursor[c], 1);
        csr[p] = (unsigned short)row[i];
    }
}

// Dual GEMM: outA = (X@WA) * dinv[row]  (source-side norm folded),
//            outB =  X@WB              (residual path, unscaled).
// A staged once (fp32->f16 if F32IN), A-fragments cached in regs across
// both B passes (LDS Bt reused).
// Fragment layouts (HW-verified, guide §3): A[m=lane&15][k=quad*8+j],
// B[k=quad*8+j][n=lane&15], C/D col=lane&15 row=quad*4+reg.
template <int F32IN>
__global__ __launch_bounds__(256) void gemm_dual_kernel(
        const void* __restrict__ Xv, const _Float16* __restrict__ WtA,
        const _Float16* __restrict__ WtB, _Float16* __restrict__ outA,
        _Float16* __restrict__ outB, const float* __restrict__ dinv, int n) {
    __shared__ _Float16 Af[64 * 136];
    __shared__ _Float16 Bt[128 * 136];
    int t = threadIdx.x;
    int r0 = blockIdx.x * 64;

    if (F32IN) {
        const float* X = (const float*)Xv;
#pragma unroll
        for (int i = 0; i < 8; ++i) {
            int flat = i * 256 + t;
            int r = flat >> 5, c4 = flat & 31;
            float4 v = make_float4(0.f, 0.f, 0.f, 0.f);
            if (r0 + r < n) v = ((const float4*)X)[(size_t)(r0 + r) * 32 + c4];
            half4 h;
            h.x = (_Float16)v.x; h.y = (_Float16)v.y;
            h.z = (_Float16)v.z; h.w = (_Float16)v.w;
            *(half4*)&Af[r * 136 + c4 * 4] = h;
        }
    } else {
        const _Float16* X = (const _Float16*)Xv;
#pragma unroll
        for (int i = 0; i < 4; ++i) {
            int flat = i * 256 + t;
            int r = flat >> 4, k8 = flat & 15;
            half8 v = {0, 0, 0, 0, 0, 0, 0, 0};
            if (r0 + r < n) v = *(const half8*)&X[(size_t)(r0 + r) * 128 + k8 * 8];
            *(half8*)&Af[r * 136 + k8 * 8] = v;
        }
    }
#pragma unroll
    for (int i = 0; i < 8; ++i) {
        int flat = i * 256 + t;
        int c = flat >> 4, k8 = flat & 15;
        *(half8*)&Bt[c * 136 + k8 * 8] = *(const half8*)&WtA[c * 128 + k8 * 8];
    }
    __syncthreads();

    int lane = t & 63, w = t >> 6;
    int m = lane & 15, q = lane >> 4;
    int rowb = r0 + w * 16 + q * 4;

    // per-output-row dinv (broadcast scalar loads, norm-folding)
    float dv[4];
#pragma unroll
    for (int r = 0; r < 4; ++r) {
        int gr = rowb + r;
        dv[r] = (gr < n) ? dinv[gr] : 0.f;
    }

    half8 a[4];
#pragma unroll
    for (int s = 0; s < 4; ++s)
        a[s] = *(const half8*)&Af[(w * 16 + m) * 136 + s * 32 + q * 8];

    floatx4 acc[8];
#pragma unroll
    for (int nt = 0; nt < 8; ++nt) acc[nt] = (floatx4){0.f, 0.f, 0.f, 0.f};
#pragma unroll
    for (int s = 0; s < 4; ++s)
#pragma unroll
        for (int nt = 0; nt < 8; ++nt) {
            half8 b = *(const half8*)&Bt[(nt * 16 + m) * 136 + s * 32 + q * 8];
            acc[nt] = __builtin_amdgcn_mfma_f32_16x16x32_f16(a[s], b, acc[nt], 0, 0, 0);
        }
    __syncthreads();
    // restage Bt with WtB; epilogue-A global stores overlap the staging
#pragma unroll
    for (int i = 0; i < 8; ++i) {
        int flat = i * 256 + t;
        int c = flat >> 4, k8 = flat & 15;
        *(half8*)&Bt[c * 136 + k8 * 8] = *(const half8*)&WtB[c * 128 + k8 * 8];
    }
#pragma unroll
    for (int nt = 0; nt < 8; ++nt) {
        int col = nt * 16 + m;
#pragma unroll
        for (int r = 0; r < 4; ++r) {
            int gr = rowb + r;
            if (gr < n) outA[(size_t)gr * 128 + col] = (_Float16)(acc[nt][r] * dv[r]);
        }
    }
    __syncthreads();

#pragma unroll
    for (int nt = 0; nt < 8; ++nt) acc[nt] = (floatx4){0.f, 0.f, 0.f, 0.f};
#pragma unroll
    for (int s = 0; s < 4; ++s)
#pragma unroll
        for (int nt = 0; nt < 8; ++nt) {
            half8 b = *(const half8*)&Bt[(nt * 16 + m) * 136 + s * 32 + q * 8];
            acc[nt] = __builtin_amdgcn_mfma_f32_16x16x32_f16(a[s], b, acc[nt], 0, 0, 0);
        }
#pragma unroll
    for (int nt = 0; nt < 8; ++nt) {
        int col = nt * 16 + m;
#pragma unroll
        for (int r = 0; r < 4; ++r) {
            int gr = rowb + r;
            if (gr < n) outB[(size_t)gr * 128 + col] = (_Float16)acc[nt][r];
        }
    }
}

// Single GEMM, f16 in / f16 out, row-scaled by dinv (norm folding).
__global__ __launch_bounds__(256) void gemm_h_kernel(
        const _Float16* __restrict__ X, const _Float16* __restrict__ Wt,
        _Float16* __restrict__ out, const float* __restrict__ dinv, int n) {
    __shared__ _Float16 Af[64 * 136];
    __shared__ _Float16 Bt[128 * 136];
    int t = threadIdx.x;
    int r0 = blockIdx.x * 64;

#pragma unroll
    for (int i = 0; i < 4; ++i) {
        int flat = i * 256 + t;
        int r = flat >> 4, k8 = flat & 15;
        half8 v = {0, 0, 0, 0, 0, 0, 0, 0};
        if (r0 + r < n) v = *(const half8*)&X[(size_t)(r0 + r) * 128 + k8 * 8];
        *(half8*)&Af[r * 136 + k8 * 8] = v;
    }
#pragma unroll
    for (int i = 0; i < 8; ++i) {
        int flat = i * 256 + t;
        int c = flat >> 4, k8 = flat & 15;
        *(half8*)&Bt[c * 136 + k8 * 8] = *(const half8*)&Wt[c * 128 + k8 * 8];
    }
    __syncthreads();

    int lane = t & 63, w = t >> 6;
    int m = lane & 15, q = lane >> 4;
    int rowb = r0 + w * 16 + q * 4;

    float dv[4];
#pragma unroll
    for (int r = 0; r < 4; ++r) {
        int gr = rowb + r;
        dv[r] = (gr < n) ? dinv[gr] : 0.f;
    }

    floatx4 acc[8];
#pragma unroll
    for (int nt = 0; nt < 8; ++nt) acc[nt] = (floatx4){0.f, 0.f, 0.f, 0.f};

#pragma unroll
    for (int s = 0; s < 4; ++s) {
        half8 a = *(const half8*)&Af[(w * 16 + m) * 136 + s * 32 + q * 8];
#pragma unroll
        for (int nt = 0; nt < 8; ++nt) {
            half8 b = *(const half8*)&Bt[(nt * 16 + m) * 136 + s * 32 + q * 8];
            acc[nt] = __builtin_amdgcn_mfma_f32_16x16x32_f16(a, b, acc[nt], 0, 0, 0);
        }
    }

#pragma unroll
    for (int nt = 0; nt < 8; ++nt) {
        int col = nt * 16 + m;
#pragma unroll
        for (int r = 0; r < 4; ++r) {
            int gr = rowb + r;
            if (gr < n) out[(size_t)gr * 128 + col] = (_Float16)(acc[nt][r] * dv[r]);
        }
    }
}

// SpMM: one 16-lane sub-group per node (4 nodes/wave), no LDS -> high
// occupancy (the R7 lesson). Lane = 16B (half8) feature slice. Edge loop
// unrolled x8 with predicated tail (clamped index, weight 0) -> 8 gathers in
// flight per row, 32 per wave.
// h is pre-scaled H' = H*dinv[src]; result multiplied by dinv[node] once
// (norm separability). Self loop: + dinv^2 * H[node] = dinv * H'[node].
// FINAL: write fp32 + bias into d_out (head folded); else f16 (+xr residual).
template <int RELU, int FINAL>
__global__ void spmm_kernel(const _Float16* __restrict__ h, const _Float16* __restrict__ xr,
                            const int* __restrict__ row_ptr,
                            const unsigned short* __restrict__ csr,
                            const float* __restrict__ dinv, _Float16* __restrict__ outh,
                            float* __restrict__ outf, const float* __restrict__ bias,
                            int n) {
    int gid = blockIdx.x * blockDim.x + threadIdx.x;
    int node = gid >> 4;
    int fl = gid & 15;   // feature slice: 8 f16 at fl*8
    if (node >= n) return;
    const half8* hp8 = (const half8*)h;

    float acc[8];
#pragma unroll
    for (int j = 0; j < 8; ++j) acc[j] = 0.f;

    int e0 = row_ptr[node], e1 = row_ptr[node + 1];
    for (int e = e0; e < e1; e += 8) {
        int src[8];
        float nn[8];
#pragma unroll
        for (int u = 0; u < 8; ++u) {
            int idx = e + u;
            int act = idx < e1;
            src[u] = csr[act ? idx : e];
            nn[u] = act ? 1.f : 0.f;
        }
        half8 v[8];
#pragma unroll
        for (int u = 0; u < 8; ++u)
            v[u] = hp8[(size_t)src[u] * 16 + fl];
#pragma unroll
        for (int u = 0; u < 8; ++u)
#pragma unroll
            for (int j = 0; j < 8; ++j)
                acc[j] = fmaf(nn[u], (float)v[u][j], acc[j]);
    }

    // self loop (h already carries dinv[src]); then dest-side dinv once
    float di = dinv[node];
    half8 hv = hp8[(size_t)node * 16 + fl];
#pragma unroll
    for (int j = 0; j < 8; ++j) acc[j] += (float)hv[j];
#pragma unroll
    for (int j = 0; j < 8; ++j) acc[j] *= di;

    if (!FINAL && xr) {
        half8 r = ((const half8*)xr)[(size_t)node * 16 + fl];
#pragma unroll
        for (int j = 0; j < 8; ++j) acc[j] += (float)r[j];
    }
    if (RELU) {
#pragma unroll
        for (int j = 0; j < 8; ++j) acc[j] = fmaxf(acc[j], 0.f);
    }
    if (FINAL) {
        float4 b0 = *(const float4*)&bias[fl * 8];
        float4 b1 = *(const float4*)&bias[fl * 8 + 4];
        float4 o0 = make_float4(acc[0] + b0.x, acc[1] + b0.y,
                                acc[2] + b0.z, acc[3] + b0.w);
        float4 o1 = make_float4(acc[4] + b1.x, acc[5] + b1.y,
                                acc[6] + b1.z, acc[7] + b1.w);
        ((float4*)outf)[(size_t)node * 32 + fl * 2] = o0;
        ((float4*)outf)[(size_t)node * 32 + fl * 2 + 1] = o1;
    } else {
        half8 o;
#pragma unroll
        for (int j = 0; j < 8; ++j) o[j] = (_Float16)acc[j];
        ((half8*)outh)[(size_t)node * 16 + fl] = o;
    }
}

extern "C" void kernel_launch(void* const* d_in, const int* in_sizes, int n_in,
                              void* d_out, int out_size, void* d_ws, size_t ws_size,
                              hipStream_t stream) {
    const float* x  = (const float*)d_in[0];
    const int*   ei = (const int*)d_in[1];
    const float* W1 = (const float*)d_in[2];
    const float* R1 = (const float*)d_in[3];
    const float* W2 = (const float*)d_in[4];
    const float* R2 = (const float*)d_in[5];
    const float* W3 = (const float*)d_in[6];
    const float* Wh = (const float*)d_in[7];
    const float* bh = (const float*)d_in[8];
    float* out = (float*)d_out;

    int N = in_sizes[0] / 128;
    int E = in_sizes[1] / 2;

    char* p = (char*)d_ws;
    auto alloc = [&](size_t bytes) {
        char* r = p;
        p += (bytes + 255) & ~(size_t)255;
        return r;
    };
    int*            cnt     = (int*)alloc((size_t)N * 4);
    int*            row_ptr = (int*)alloc((size_t)(N + 1) * 4);
    int*            cursor  = (int*)alloc((size_t)N * 4);
    float*          dinv    = (float*)alloc((size_t)N * 4);
    unsigned short* csr     = (unsigned short*)alloc((size_t)E * 2);
    _Float16*       Wt      = (_Float16*)alloc((size_t)5 * 16384 * 2);
    _Float16*       B0h     = (_Float16*)alloc((size_t)N * 128 * 2);
    _Float16*       B1h     = (_Float16*)alloc((size_t)N * 128 * 2);
    _Float16*       B2h     = (_Float16*)alloc((size_t)N * 128 * 2);

    const int* rowi = ei;
    const int* coli = ei + E;

    int nb = (N + SCAN_CHUNK - 1) / SCAN_CHUNK;
    int nzb = (N + 255) / 256;

    prep0_kernel<<<nzb + 80, 256, 0, stream>>>(cnt, N, nzb, W1, R1, W2, R2, W3, Wh, Wt);
    hist_kernel<<<(E + 255) / 256, 256, 0, stream>>>(coli, cnt, E);
    scan_fused_kernel<<<nb, 256, 0, stream>>>(cnt, row_ptr, cursor, dinv, N, E);
    fill_kernel<<<(E + 255) / 256, 256, 0, stream>>>(rowi, coli, cursor, csr, E);

    int gb = (N + 63) / 64;
    int sb = ((size_t)N * 16 + 255) / 256;
    _Float16* Wt1 = Wt;
    _Float16* Rt1 = Wt + 16384;
    _Float16* Wt2 = Wt + 2 * 16384;
    _Float16* Rt2 = Wt + 3 * 16384;
    _Float16* Wtc = Wt + 4 * 16384;

    // layer 1: H'=B0h (scaled), XR=B1h, x1 -> B1h
    gemm_dual_kernel<1><<<gb, 256, 0, stream>>>(x, Wt1, Rt1, B0h, B1h, dinv, N);
    spmm_kernel<1, 0><<<sb, 256, 0, stream>>>(B0h, B1h, row_ptr, csr, dinv,
                                              B1h, nullptr, nullptr, N);
    // layer 2: H'=B0h, XR=B2h, x2 -> B2h
    gemm_dual_kernel<0><<<gb, 256, 0, stream>>>(B1h, Wt2, Rt2, B0h, B2h, dinv, N);
    spmm_kernel<1, 0><<<sb, 256, 0, stream>>>(B0h, B2h, row_ptr, csr, dinv,
                                              B2h, nullptr, nullptr, N);
    // layer 3 + head (linearity): G' = dinv*(x2@(W3@Wh)); out = dinv*(A@G') + bh
    gemm_h_kernel<<<gb, 256, 0, stream>>>(B2h, Wtc, B0h, dinv, N);
    spmm_kernel<0, 1><<<sb, 256, 0, stream>>>(B0h, nullptr, row_ptr, csr, dinv,
                                              nullptr, out, bh, N);
}